// Round 11
// baseline (97.258 us; speedup 1.0000x reference)
//
#include <hip/hip_runtime.h>
#include <cmath>

#define Nn 200000
#define CAP 1024      // merged candidate capacity (typ. ~390)
#define CAPQ 256      // per-wave (eighth) capacity
#define ESZ 25000     // ints per wave segment (Nn/8)
#define EI4 6250      // int4 per segment
#define NIT 98        // ceil(6250/64)
#define N4TOT 12800064 // (256 + 256*200000)/4 : fills ALL of d_out exactly
#define NCOMP 256
#define NFILL 768
#define NBLK1 1024

__device__ __forceinline__ bool mask_at(const void* m, size_t idx, int isbyte) {
    if (isbyte) return ((const unsigned char*)m)[idx] != 0;
    return ((const unsigned int*)m)[idx] != 0u;
}

// ---------------- k1: compute rows (blocks 0..255) + bulk zero-fill (256..1023) ----------------
__global__ __launch_bounds__(512) void k1(
    const float* __restrict__ q, const float* __restrict__ lib,
    const void* __restrict__ mask, const int* __restrict__ lib_wp,
    const int* __restrict__ wp_id, const float* __restrict__ log_tau,
    float* __restrict__ out,
    int* __restrict__ nlist_g, float* __restrict__ pv_g, float* __restrict__ ctxws,
    int* __restrict__ dense_g, int* __restrict__ szr_g, int* __restrict__ isb_g) {
    int bid = blockIdx.x, t = threadIdx.x;
    if (bid >= NCOMP) {
        // ---- bulk zero-fill: 768 blocks x 8 waves, grid-stride, coalesced ----
        float4* p = (float4*)out;
        const float4 z = make_float4(0.f, 0.f, 0.f, 0.f);
        int stride = NFILL * 512;
#pragma unroll 4
        for (int i = (bid - NCOMP) * 512 + t; i < N4TOT; i += stride) p[i] = z;
        return;
    }
    __shared__ int qlist[8 * CAPQ];
    __shared__ int qcnt[8];
    __shared__ int nlist[CAP];
    __shared__ float svals[CAP];
    __shared__ unsigned char vbit[CAP];
    __shared__ float ltile[64 * 65];      // stride 65: conflict-free
    __shared__ float q_s[64], pbuf[64];
    __shared__ int isb_s;

    int b = bid;
    int wv = t >> 6, lane = t & 63;
    int wpb = wp_id[b];

    // ---- phase A: 8-wave int4 stable compaction scan (R10-verified) ----
    if (wv == 0) {
        const uint4* mw4 = (const uint4*)mask;
        int f = 0;
        for (int i = lane; i < 1024; i += 64) {
            uint4 x = mw4[i];
            if ((x.x >= 2u && x.x != 0x3F800000u) || (x.y >= 2u && x.y != 0x3F800000u) ||
                (x.z >= 2u && x.z != 0x3F800000u) || (x.w >= 2u && x.w != 0x3F800000u))
                f = 1;
        }
        unsigned long long bal = __ballot(f != 0);
        if (lane == 0) isb_s = bal ? 1 : 0;
    }
    {
        const int4* seg = (const int4*)(lib_wp + wv * ESZ);
        int cnt = 0;
        int pad = wpb ^ 1;                 // guaranteed != wpb
#pragma unroll 4
        for (int it = 0; it < NIT; ++it) {
            int i = it * 64 + lane;
            int4 v = (i < EI4) ? seg[i] : make_int4(pad, pad, pad, pad);
            int m0 = (v.x == wpb) ? 1 : 0;
            int m1 = (v.y == wpb) ? 1 : 0;
            int m2 = (v.z == wpb) ? 1 : 0;
            int m3 = (v.w == wpb) ? 1 : 0;
            int mc = m0 + m1 + m2 + m3;
            unsigned long long anyb = __ballot(mc != 0);   // wave-uniform
            if (anyb) {
                int inc = mc;
#pragma unroll
                for (int o = 1; o < 64; o <<= 1) {
                    int x = __shfl_up(inc, o, 64);
                    if (lane >= o) inc += x;
                }
                int excl = inc - mc;
                int wtot = __shfl(inc, 63, 64);
                int pos = cnt + excl;
                int nb = wv * ESZ + i * 4;
                if (m0) { if (pos < CAPQ) qlist[wv * CAPQ + pos] = nb;     pos++; }
                if (m1) { if (pos < CAPQ) qlist[wv * CAPQ + pos] = nb + 1; pos++; }
                if (m2) { if (pos < CAPQ) qlist[wv * CAPQ + pos] = nb + 2; pos++; }
                if (m3) { if (pos < CAPQ) qlist[wv * CAPQ + pos] = nb + 3; pos++; }
                cnt += wtot;
            }
        }
        if (lane == 0) qcnt[wv] = cnt;
    }
    __syncthreads();
    if (wv != 0) return;                   // waves 1-7 done

    // ---- phase B (wave 0): merge + mask gather + count + flash softmax ----
    int isb = isb_s;
    int cs[8];
    int sz = 0;
    bool ov = false;
#pragma unroll
    for (int k = 0; k < 8; ++k) {
        int c = qcnt[k];
        cs[k] = c; sz += c;
        if (c > CAPQ) ov = true;
    }
    if (sz > CAP) ov = true;
    int cntv = 0;
    if (!ov) {
        int base = 0;
#pragma unroll
        for (int k = 0; k < 8; ++k) {
            for (int i = lane; i < cs[k]; i += 64) {
                int n = qlist[k * CAPQ + i];
                nlist[base + i] = n;
                nlist_g[(size_t)b * CAP + base + i] = n;
            }
            base += cs[k];
        }
        asm volatile("s_waitcnt lgkmcnt(0)" ::: "memory");
        for (int i = lane; i < sz; i += 64) {
            int n = nlist[i];
            bool v = !mask_at(mask, (size_t)b * Nn + n, isb);
            vbit[i] = v ? 1 : 0;
            cntv += v ? 1 : 0;
        }
#pragma unroll
        for (int o = 1; o < 64; o <<= 1) cntv += __shfl_xor(cntv, o, 64);
    }
    bool sf = (!ov) && (cntv >= 8);
    if (lane == 0) {
        dense_g[b] = sf ? 0 : 1;
        szr_g[b] = sz;
        if (b == 0) isb_g[0] = isb;
    }
    if (!sf) return;

    q_s[lane] = q[b * 64 + lane];
    float tau = expf(log_tau[0]);
    tau = fminf(fmaxf(tau, 1e-3f), 10.0f);
    float inv_tau = 1.0f / tau;
    float Ms = -INFINITY, Ss = 0.f, ctxp = 0.f;
    for (int cc = 0; cc < sz; cc += 64) {
        int cn = min(64, sz - cc);
        if (lane < cn) {
            int n_i = nlist[cc + lane];
            const float4* src = (const float4*)&lib[(size_t)n_i * 64];
            float* dst = &ltile[lane * 65];
#pragma unroll
            for (int p4 = 0; p4 < 16; ++p4) {
                float4 v = src[p4];
                dst[p4 * 4] = v.x; dst[p4 * 4 + 1] = v.y;
                dst[p4 * 4 + 2] = v.z; dst[p4 * 4 + 3] = v.w;
            }
        }
        asm volatile("s_waitcnt lgkmcnt(0)" ::: "memory");
        float s = -INFINITY;
        if (lane < cn && vbit[cc + lane]) {
            float acc = 0.f;
#pragma unroll
            for (int dd = 0; dd < 64; ++dd)
                acc = fmaf(q_s[dd], ltile[lane * 65 + dd], acc);
            s = acc * inv_tau;
        }
        if (lane < cn) svals[cc + lane] = s;
        float m = s;
#pragma unroll
        for (int o = 1; o < 64; o <<= 1) m = fmaxf(m, __shfl_xor(m, o, 64));
        float e = (s > -INFINITY) ? expf(s - m) : 0.f;
#pragma unroll
        for (int o = 1; o < 64; o <<= 1) e += __shfl_xor(e, o, 64);
        float scl = 1.f;
        float newM = fmaxf(Ms, m);
        if (newM > -INFINITY) {
            scl = expf(Ms - newM);             // Ms=-inf -> 0 (safe)
            Ss = Ss * scl + e * expf(m - newM);
            Ms = newM;
        }
        ctxp *= scl;                           // flash rescale
        pbuf[lane] = (s > -INFINITY) ? expf(s - Ms) : 0.f;
        asm volatile("s_waitcnt lgkmcnt(0)" ::: "memory");
        for (int i2 = 0; i2 < cn; ++i2)
            ctxp = fmaf(pbuf[i2], ltile[i2 * 65 + lane], ctxp);
    }
    float invS = 1.0f / Ss;
    ctxws[b * 64 + lane] = ctxp * invS;
    for (int i = lane; i < sz; i += 64) {
        float s2 = svals[i];
        pv_g[(size_t)b * CAP + i] = (s2 > -INFINITY) ? expf(s2 - Ms) * invS : 0.f;
    }
}

// ---------------- k2: scatter p over zeros (or dense fallback) + MLP head ----------------
__global__ __launch_bounds__(256) void k2(
    const float* __restrict__ q, const float* __restrict__ lib,
    const void* __restrict__ mask, const int* __restrict__ lib_wp,
    const int* __restrict__ wp_id, const int* __restrict__ action_id,
    const float* __restrict__ wp_prior, const float* __restrict__ act_emb,
    const float* __restrict__ W1, const float* __restrict__ b1,
    const float* __restrict__ W2, const float* __restrict__ b2,
    const float* __restrict__ log_tau, const float* __restrict__ plw,
    float* __restrict__ out,
    const int* __restrict__ nlist_g, const float* __restrict__ pv_g,
    float* __restrict__ ctxws, const int* __restrict__ dense_g,
    const int* __restrict__ szr_g, const int* __restrict__ isb_g) {
    __shared__ float q_s[64];
    __shared__ float redm[4], reds[4];
    __shared__ float Msh, Ssh;
    __shared__ float pbuf2[256];
    __shared__ int redci[256];
    int b = blockIdx.x, t = threadIdx.x;
    float* attnrow = out + 256 + (size_t)b * Nn;
    int dense = dense_g[b];
    int wpb = wp_id[b];

    if (!dense) {
        int sz = szr_g[b];
        for (int i = t; i < sz; i += 256)
            attnrow[nlist_g[(size_t)b * CAP + i]] = pv_g[(size_t)b * CAP + i];
    } else {
        // ---- dense fallback (rare/never): recount, then full reference formula ----
        int isb = isb_g[0];
        int cntd = 0;
        for (int c0 = 0; c0 < Nn; c0 += 256) {
            int n = c0 + t;
            if (n < Nn && lib_wp[n] == wpb && !mask_at(mask, (size_t)b * Nn + n, isb))
                cntd++;
        }
        redci[t] = cntd;
        __syncthreads();
        for (int s2 = 128; s2 > 0; s2 >>= 1) {
            if (t < s2) redci[t] += redci[t + s2];
            __syncthreads();
        }
        int sfb = (redci[0] >= 8) ? 1 : 0;
        if (t < 64) q_s[t] = q[b * 64 + t];
        if (t == 0) { Msh = -INFINITY; Ssh = 0.f; }
        float tau = expf(log_tau[0]);
        tau = fminf(fmaxf(tau, 1e-3f), 10.0f);
        float inv_tau = 1.0f / tau;
        __syncthreads();
        for (int c0 = 0; c0 < Nn; c0 += 256) {
            int n = c0 + t;
            float s = -INFINITY;
            if (n < Nn) {
                bool mk = mask_at(mask, (size_t)b * Nn + n, isb);
                bool wpm = (lib_wp[n] == wpb);
                if (!mk && !(sfb && !wpm)) {
                    float acc = 0.f;
#pragma unroll
                    for (int dd = 0; dd < 64; dd += 4) {
                        float4 v = *(const float4*)&lib[(size_t)n * 64 + dd];
                        acc = fmaf(q_s[dd], v.x, acc);
                        acc = fmaf(q_s[dd + 1], v.y, acc);
                        acc = fmaf(q_s[dd + 2], v.z, acc);
                        acc = fmaf(q_s[dd + 3], v.w, acc);
                    }
                    s = acc * inv_tau;
                }
                attnrow[n] = s;
            }
            float m = s;
#pragma unroll
            for (int o = 1; o < 64; o <<= 1) m = fmaxf(m, __shfl_xor(m, o, 64));
            float e = (s > -INFINITY) ? expf(s - m) : 0.f;
#pragma unroll
            for (int o = 1; o < 64; o <<= 1) e += __shfl_xor(e, o, 64);
            if ((t & 63) == 0) { redm[t >> 6] = m; reds[t >> 6] = e; }
            __syncthreads();
            if (t == 0) {
                for (int g = 0; g < 4; ++g) {
                    float m2 = redm[g], e2 = reds[g];
                    if (m2 > -INFINITY) {
                        if (m2 > Msh) { Ssh = Ssh * expf(Msh - m2) + e2; Msh = m2; }
                        else          { Ssh += e2 * expf(m2 - Msh); }
                    }
                }
            }
            __syncthreads();
        }
        float M = Msh, invS = 1.0f / Ssh;
        int d = t & 63, g = t >> 6;
        float ctxp = 0.f;
        for (int c0 = 0; c0 < Nn; c0 += 256) {
            int n = c0 + t;
            float p = 0.f;
            if (n < Nn) {
                float s = attnrow[n];
                p = (s > -INFINITY) ? expf(s - M) * invS : 0.f;
                attnrow[n] = p;
            }
            pbuf2[t] = p;
            __syncthreads();
            int lim = min(256, Nn - c0);
            for (int i2 = g; i2 < lim; i2 += 4) {
                float p2 = pbuf2[i2];
                if (p2 != 0.f) ctxp = fmaf(p2, lib[(size_t)(c0 + i2) * 64 + d], ctxp);
            }
            __syncthreads();
        }
        pbuf2[t] = ctxp;
        __syncthreads();
        if (t < 64)
            ctxws[b * 64 + t] = pbuf2[t] + pbuf2[64 + t] + pbuf2[128 + t] + pbuf2[192 + t];
    }
    __syncthreads();
    // ---- MLP head + prior (threads 0..63 = wave 0) ----
    if (t < 64) {
        int j = t;
        float ctx = ctxws[b * 64 + j];
        float acc = b1[j];
        int aid = action_id[b];
        for (int i = 0; i < 64; ++i) acc = fmaf(q[b * 64 + i], W1[i * 64 + j], acc);
        for (int i = 0; i < 64; ++i) acc = fmaf(__shfl(ctx, i, 64), W1[(64 + i) * 64 + j], acc);
        for (int i = 0; i < 6; ++i) acc = fmaf(act_emb[aid * 6 + i], W1[(128 + i) * 64 + j], acc);
        float h1 = 0.5f * acc * (1.0f + erff(acc * 0.70710678118654752f));
        float v = h1 * W2[j];
#pragma unroll
        for (int o = 1; o < 64; o <<= 1) v += __shfl_xor(v, o, 64);
        if (j == 0) {
            float pr = fminf(fmaxf(wp_prior[b], 1e-3f), 1.0f - 1e-3f);
            float pl = logf(pr) - log1pf(-pr);
            out[b] = v + b2[0] + plw[0] * pl;
        }
    }
}

extern "C" void kernel_launch(void* const* d_in, const int* in_sizes, int n_in,
                              void* d_out, int out_size, void* d_ws, size_t ws_size,
                              hipStream_t stream) {
    const float* q = (const float*)d_in[0];
    const float* lib = (const float*)d_in[1];
    const void* mask = d_in[2];
    const int* lib_wp = (const int*)d_in[3];
    const int* wp_id = (const int*)d_in[4];
    const int* action_id = (const int*)d_in[5];
    const float* wp_prior = (const float*)d_in[6];
    const float* act_emb = (const float*)d_in[7];
    const float* W1 = (const float*)d_in[8];
    const float* b1 = (const float*)d_in[9];
    const float* W2 = (const float*)d_in[10];
    const float* b2 = (const float*)d_in[11];
    const float* log_tau = (const float*)d_in[12];
    const float* plw = (const float*)d_in[13];
    float* out = (float*)d_out;

    char* ws = (char*)d_ws;
    int* dense_g = (int*)(ws + 0);           // 256 ints
    int* szr_g   = (int*)(ws + 1024);        // 256 ints
    int* isb_g   = (int*)(ws + 2048);        // 1 int
    float* ctxws = (float*)(ws + 4096);      // 256*64 floats = 64 KB
    int* nlist_g = (int*)(ws + 69632);       // 256*1024 ints = 1 MB
    float* pv_g  = (float*)(ws + 69632 + 1048576);  // 1 MB

    k1<<<dim3(NBLK1), 512, 0, stream>>>(q, lib, mask, lib_wp, wp_id, log_tau, out,
                                        nlist_g, pv_g, ctxws, dense_g, szr_g, isb_g);
    k2<<<dim3(256), 256, 0, stream>>>(q, lib, mask, lib_wp, wp_id, action_id, wp_prior,
                                      act_emb, W1, b1, W2, b2, log_tau, plw, out,
                                      nlist_g, pv_g, ctxws, dense_g, szr_g, isb_g);
}